// Round 6
// baseline (408.798 us; speedup 1.0000x reference)
//
#include <hip/hip_runtime.h>
#include <math.h>

#define D_DIM 3072
#define H_DIM 1024
#define Z_DIM 32
#define BATCH 128
#define NNEI 32
#define NROWS (BATCH * NNEI) /* 4096 */
#define MENC (NROWS + BATCH) /* 4224 */

typedef __attribute__((ext_vector_type(8))) short short8;
typedef __attribute__((ext_vector_type(4))) float f32x4;
typedef unsigned short ushortT;

__device__ __forceinline__ unsigned short f2bf(float f) {
  union { float f; unsigned int u; } v; v.f = f;
  unsigned int r = v.u + 0x7FFFu + ((v.u >> 16) & 1u);
  return (unsigned short)(r >> 16);
}
__device__ __forceinline__ float bf2f(unsigned short b) {
  union { unsigned int u; float f; } v; v.u = ((unsigned int)b) << 16;
  return v.f;
}

// Async global->LDS, 16B per lane (gemm_sb only).
__device__ __forceinline__ void gl16(const ushortT* g, ushortT* l) {
  typedef __attribute__((address_space(1))) const void gvoid;
  typedef __attribute__((address_space(3))) void lvoid;
  __builtin_amdgcn_global_load_lds((gvoid*)(const void*)g, (lvoid*)(void*)l,
                                   16, 0, 0);
}
typedef __attribute__((address_space(3))) const ushortT lds_cus;
__device__ __forceinline__ short8 ldsr(const ushortT* p) {
  short8 r;
  asm volatile("ds_read_b128 %0, %1" : "=v"(r) : "v"((lds_cus*)p));
  return r;
}
#define BAR() asm volatile("s_barrier" ::: "memory")
#define VM0() asm volatile("s_waitcnt vmcnt(0)" ::: "memory")
#define LGKM0() asm volatile("s_waitcnt lgkmcnt(0)" ::: "memory")

enum { EP_RELU = 0, EP_BIAS = 1, EP_PART = 2, EP_LOSS = 3 };

// R15: register-relay GEMM (R0's measured-best inner loop) + streams.
// R14 post-mortem: gload_lds structures are pinned at ~5100 cyc/BK32
// per-block serial REGARDLESS of sync scheme (R11/12/13/14); only stream
// count ever multiplied throughput (R12: 3x). R0's relay measured 2350
// cyc/BK32 serial at 1 stream: named uint4 staging gives the compiler
// precise per-register vmcnt -- the ds_write of iter k waits on loads
// issued one full iteration (~4700 cyc) earlier. Natural deep pipeline.
// So: R0 loop verbatim; occupancy un-capped (waves_per_eu(4); 32KB LDS +
// 88 VGPR => up to 5 blocks/CU); split-K grids for >=4 streams.
// Staging: 8 named uint4/thread -- SROA-safe (R5/R6: array-through-pointer
// staging spills). LDS fragment order per k-half kh (4096 elem): chunk c
// (16 rows) at c*512, lane (lm,quad) fragment at lane*8 -- conflict-free
// b128 writes/reads.
// Per iter: barrier; ds_write(regs, vmcnt per-reg: loads 1 iter old);
// barrier; load(k+1); compute 2 k-halves (2 x [8 ds_read_b128, 16 MFMA]).
// A: MxK bf16 row-major, BT: NxK bf16. M%128==0, N%TN==0, Ks%64==0.
template <int MODE, int TN>
__global__ __launch_bounds__(256) __attribute__((amdgpu_waves_per_eu(4)))
void gemm64(
    const ushortT* __restrict__ A, const ushortT* __restrict__ BT,
    const float* __restrict__ bias, ushortT* __restrict__ C,
    float* __restrict__ P, int M, int N, int K, int Ks,
    const ushortT* __restrict__ xa,    // EP_LOSS: M x N bf16 (x_nn)
    const float* __restrict__ wrow,    // EP_LOSS: per-row weight
    float* __restrict__ out) {
  constexpr int NF = TN / 32;  // 4 (TN=128) or 1 (TN=32)

  __shared__ __align__(16) ushortT As[8192];      // 128 x 64
  __shared__ __align__(16) ushortT Bs[TN * 64];

  const int t = threadIdx.x;
  const int wave = t >> 6;
  const int lane = t & 63;
  const int quad = lane >> 4;
  const int lm = lane & 15;

  // XCD-bijective swizzle (FETCH 105->42MB, kept). Only when nwg%8==0.
  int id = blockIdx.y * gridDim.x + blockIdx.x;
  const int nwg = gridDim.x * gridDim.y;
  if ((nwg & 7) == 0) id = (id & 7) * (nwg >> 3) + (id >> 3);
  const int bm = (id / gridDim.x) * 128;
  const int bn = (id % gridDim.x) * TN;

  const int koff = blockIdx.z * Ks;
  const int wr = (wave >> 1) * 64;
  const int wc = (wave & 1) * (TN / 2);

  f32x4 acc[4][NF];
#pragma unroll
  for (int i = 0; i < 4; ++i)
#pragma unroll
    for (int j = 0; j < NF; ++j) acc[i][j] = (f32x4)0.f;

  // A staging: thread t owns LDS slots {t, t+256, t+512, t+768}:
  //   t      -> kh0, rows (t>>6)*16+(t&15),      k ((t>>4)&3)*8
  //   t+256  -> kh0, rows +64
  //   t+512  -> kh1 (k +32), rows as t
  //   t+768  -> kh1, rows +64
  const int a_r0 = (t >> 6) * 16 + (t & 15);
  const int a_q8 = ((t >> 4) & 3) * 8;
  const ushortT* ga = A + (size_t)(bm + a_r0) * K + koff + a_q8;
  const size_t aK64 = (size_t)64 * K;

  const ushortT* gb = nullptr;
  if (TN == 128) {
    gb = BT + (size_t)(bn + a_r0) * K + koff + a_q8;
  } else {
    // B tile 32x64 = 256 slots, 1/thread: slot t -> kh=t>>7, c=(t>>6)&1
    const int b_r = ((t >> 6) & 1) * 16 + (t & 15);
    const int b_k = (t >> 7) * 32 + ((t >> 4) & 3) * 8;
    gb = BT + (size_t)(bn + b_r) * K + koff + b_k;
  }

  uint4 a0, a1, a2, a3, b0, b1 = {0,0,0,0}, b2 = {0,0,0,0}, b3 = {0,0,0,0};

#define LOADT(kk)                                               \
  {                                                             \
    const size_t o = (size_t)(kk) * 64;                         \
    a0 = *(const uint4*)(ga + o);                               \
    a1 = *(const uint4*)(ga + aK64 + o);                        \
    a2 = *(const uint4*)(ga + o + 32);                          \
    a3 = *(const uint4*)(ga + aK64 + o + 32);                   \
    b0 = *(const uint4*)(gb + o);                               \
    if (TN == 128) {                                            \
      b1 = *(const uint4*)(gb + aK64 + o);                      \
      b2 = *(const uint4*)(gb + o + 32);                        \
      b3 = *(const uint4*)(gb + aK64 + o + 32);                 \
    }                                                           \
  }
#define STORET()                                                \
  {                                                             \
    *(uint4*)&As[t * 8] = a0;                                   \
    *(uint4*)&As[t * 8 + 2048] = a1;                            \
    *(uint4*)&As[t * 8 + 4096] = a2;                            \
    *(uint4*)&As[t * 8 + 6144] = a3;                            \
    if (TN == 128) {                                            \
      *(uint4*)&Bs[t * 8] = b0;                                 \
      *(uint4*)&Bs[t * 8 + 2048] = b1;                          \
      *(uint4*)&Bs[t * 8 + 4096] = b2;                          \
      *(uint4*)&Bs[t * 8 + 6144] = b3;                          \
    } else {                                                    \
      *(uint4*)&Bs[t * 8] = b0;                                 \
    }                                                           \
  }

  const int nk = Ks / 64;
  LOADT(0);

  for (int k0 = 0; k0 < nk; ++k0) {
    __syncthreads();   // prior iteration's LDS reads complete
    STORET();          // vmcnt per-reg: loads issued ~1 full iter ago
    __syncthreads();
    if (k0 + 1 < nk) LOADT(k0 + 1);

#pragma unroll
    for (int kk = 0; kk < 2; ++kk) {
      const ushortT* arp = &As[kk * 4096 + (wr >> 4) * 512 + lane * 8];
      const ushortT* brp = (TN == 128)
          ? &Bs[kk * 4096 + (wc >> 4) * 512 + lane * 8]
          : &Bs[kk * 1024 + (wc >> 4) * 512 + lane * 8];
      short8 af[4], bf[NF];
#pragma unroll
      for (int mt = 0; mt < 4; ++mt) af[mt] = *(const short8*)(arp + mt * 512);
#pragma unroll
      for (int nt = 0; nt < NF; ++nt) bf[nt] = *(const short8*)(brp + nt * 512);
#pragma unroll
      for (int mt = 0; mt < 4; ++mt)
#pragma unroll
        for (int nt = 0; nt < NF; ++nt)
          acc[mt][nt] = __builtin_amdgcn_mfma_f32_16x16x32_bf16(af[mt], bf[nt], acc[mt][nt], 0, 0, 0);
    }
  }
#undef LOADT
#undef STORET

  // C/D layout: col = lane&15, row = quad*4 + reg
  if (MODE == EP_LOSS) {
    __shared__ float red[256];
    float lsum = 0.f;
#pragma unroll
    for (int mt = 0; mt < 4; ++mt) {
#pragma unroll
      for (int r = 0; r < 4; ++r) {
        const int row = bm + wr + mt * 16 + quad * 4 + r;
        const float w = wrow[row];
        const ushortT* xr = xa + (size_t)row * N;
        float rs = 0.f;
#pragma unroll
        for (int nt = 0; nt < NF; ++nt) {
          const int col = bn + wc + nt * 16 + lm;
          const float d = bf2f(xr[col]) - (acc[mt][nt][r] + bias[col]);
          rs = fmaf(d, d, rs);
        }
        lsum = fmaf(w, rs, lsum);
      }
    }
    __syncthreads();
    red[t] = lsum;
    __syncthreads();
    for (int st = 128; st > 0; st >>= 1) {
      if (t < st) red[t] += red[t + st];
      __syncthreads();
    }
    if (t == 0) atomicAdd(out, red[0] * (1.0f / (float)NROWS));
  } else if (MODE == EP_PART) {
#pragma unroll
    for (int mt = 0; mt < 4; ++mt)
#pragma unroll
      for (int r = 0; r < 4; ++r) {
        const int row = bm + wr + mt * 16 + quad * 4 + r;
#pragma unroll
        for (int nt = 0; nt < NF; ++nt) {
          const int col = bn + wc + nt * 16 + lm;
          P[((size_t)blockIdx.z * M + row) * N + col] = acc[mt][nt][r];
        }
      }
  } else {
#pragma unroll
    for (int mt = 0; mt < 4; ++mt)
#pragma unroll
      for (int r = 0; r < 4; ++r) {
        const int row = bm + wr + mt * 16 + quad * 4 + r;
#pragma unroll
        for (int nt = 0; nt < NF; ++nt) {
          const int col = bn + wc + nt * 16 + lm;
          float v = acc[mt][nt][r] + bias[col];
          if (MODE == EP_RELU) v = fmaxf(v, 0.f);
          C[(size_t)row * N + col] = f2bf(v);
        }
      }
  }
}

// Single K=32 tile GEMM (dec L1 only): gload_lds + vmcnt(0) + one compute.
template <int MODE, int TN>
__global__ __launch_bounds__(256) void gemm_sb(
    const ushortT* __restrict__ A, const ushortT* __restrict__ BT,
    const float* __restrict__ bias, ushortT* __restrict__ C,
    int M, int N, int K,   // K must be 32
    const ushortT* __restrict__ xa, const float* __restrict__ wrow,
    float* __restrict__ out) {
  constexpr int NF = TN / 32;
  __shared__ __align__(16) ushortT As[4096];
  __shared__ __align__(16) ushortT Bs[TN * 32];

  const int t = threadIdx.x;
  const int wave = t >> 6;
  const int lane = t & 63;
  const int quad = lane >> 4;
  const int lm = lane & 15;

  int id = blockIdx.y * gridDim.x + blockIdx.x;
  const int nwg = gridDim.x * gridDim.y;
  if ((nwg & 7) == 0) id = (id & 7) * (nwg >> 3) + (id >> 3);
  const int bm = (id / gridDim.x) * 128;
  const int bn = (id % gridDim.x) * TN;

  const int wr = (wave >> 1) * 64;
  const int wc = (wave & 1) * (TN / 2);

  const int a_r0 = (t >> 6) * 16 + (t & 15);
  const int a_q8 = ((t >> 4) & 3) * 8;
  const ushortT* ga0 = A + (size_t)(bm + a_r0) * K + a_q8;
  const ushortT* gb0 = BT + (size_t)(bn + a_r0) * K + a_q8;

  ushortT* asw = &As[wave * 512];
  ushortT* bsw = &Bs[wave * 512];
  gl16(ga0, asw);
  gl16(ga0 + (size_t)64 * K, asw + 2048);
  gl16(gb0, bsw);
  if (TN == 128) gl16(gb0 + (size_t)64 * K, bsw + 2048);
  VM0();
  BAR();

  f32x4 acc[4][NF];
#pragma unroll
  for (int i = 0; i < 4; ++i)
#pragma unroll
    for (int j = 0; j < NF; ++j) acc[i][j] = (f32x4)0.f;

  const ushortT* arp = As + (wr >> 4) * 512 + lane * 8;
  const ushortT* brp = Bs + (wc >> 4) * 512 + lane * 8;
  short8 af[4], bf[NF];
#pragma unroll
  for (int mt = 0; mt < 4; ++mt) af[mt] = ldsr(arp + mt * 512);
#pragma unroll
  for (int nt = 0; nt < NF; ++nt) bf[nt] = ldsr(brp + nt * 512);
  LGKM0();
  __builtin_amdgcn_sched_barrier(0);
#pragma unroll
  for (int mt = 0; mt < 4; ++mt)
#pragma unroll
    for (int nt = 0; nt < NF; ++nt)
      acc[mt][nt] = __builtin_amdgcn_mfma_f32_16x16x32_bf16(
          af[mt], bf[nt], acc[mt][nt], 0, 0, 0);

#pragma unroll
  for (int mt = 0; mt < 4; ++mt)
#pragma unroll
    for (int r = 0; r < 4; ++r) {
      const int row = bm + wr + mt * 16 + quad * 4 + r;
#pragma unroll
      for (int nt = 0; nt < NF; ++nt) {
        const int col = bn + wc + nt * 16 + lm;
        float v = acc[mt][nt][r] + bias[col];
        if (MODE == EP_RELU) v = fmaxf(v, 0.f);
        C[(size_t)row * N + col] = f2bf(v);
      }
    }
}

// sum split-K fp32 partials + bias (+optional relu) -> bf16. N power of 2.
template <int S, int RELU>
__global__ __launch_bounds__(256) void reduce_lin(
    const float* __restrict__ P, const float* __restrict__ bias,
    ushortT* __restrict__ outp, int MN, int Nmask) {
  const int i4 = (blockIdx.x * 256 + threadIdx.x) * 4;
  if (i4 >= MN) return;
  float4 s = *(const float4*)(P + i4);
#pragma unroll
  for (int k = 1; k < S; ++k) {
    const float4 q = *(const float4*)(P + (size_t)k * MN + i4);
    s.x += q.x; s.y += q.y; s.z += q.z; s.w += q.w;
  }
  const float4 b = *(const float4*)(bias + (i4 & Nmask));
  float vx = s.x + b.x, vy = s.y + b.y, vz = s.z + b.z, vw = s.w + b.w;
  if (RELU) {
    vx = fmaxf(vx, 0.f); vy = fmaxf(vy, 0.f);
    vz = fmaxf(vz, 0.f); vw = fmaxf(vw, 0.f);
  }
  ushort4 o;
  o.x = f2bf(vx); o.y = f2bf(vy); o.z = f2bf(vz); o.w = f2bf(vw);
  *(ushort4*)(outp + i4) = o;
}

// Frozen-mask apply on raw pre-activations U (rows x 1024 bf16):
// rows < 4096 (neighbors): out = (U[center_row] > 0) ? U : 0
// rows >= 4096 (centers):  out = relu(U)
__global__ __launch_bounds__(256) void mask_apply(
    const ushortT* __restrict__ U, ushortT* __restrict__ outp) {
  const int i4 = (blockIdx.x * 256 + threadIdx.x) * 4;
  const int r = i4 >> 10;
  const int c = i4 & 1023;
  ushort4 u = *(const ushort4*)(U + i4);
  ushort4 o;
  if (r < NROWS) {
    const ushort4 m = *(const ushort4*)(U + (((size_t)(NROWS + (r >> 5))) << 10) + c);
    o.x = ((short)m.x > 0) ? u.x : 0;
    o.y = ((short)m.y > 0) ? u.y : 0;
    o.z = ((short)m.z > 0) ? u.z : 0;
    o.w = ((short)m.w > 0) ? u.w : 0;
  } else {
    o.x = ((short)u.x > 0) ? u.x : 0;
    o.y = ((short)u.y > 0) ? u.y : 0;
    o.z = ((short)u.z > 0) ? u.z : 0;
    o.w = ((short)u.w > 0) ? u.w : 0;
  }
  *(ushort4*)(outp + i4) = o;
}

// Fused prep: x fp32 -> bf16 A_enc; per-(b,n) weights from dist^2; zero out[0].
__global__ __launch_bounds__(256) void prep_kernel(
    const float* __restrict__ x_c, const float* __restrict__ x_nn,
    ushortT* __restrict__ A_enc, float* __restrict__ wbuf, float* __restrict__ out) {
  const int i = blockIdx.x;
  const int t = threadIdx.x;
  if (i < NROWS) {
    const float* src = x_nn + (size_t)i * D_DIM;
    const float* ctr = x_c + (size_t)(i >> 5) * D_DIM;
    ushortT* dst = A_enc + (size_t)i * D_DIM;
    float s = 0.f;
    for (int d = t * 4; d < D_DIM; d += 1024) {
      const float4 v = *(const float4*)(src + d);
      const float4 c = *(const float4*)(ctr + d);
      ushort4 o;
      o.x = f2bf(v.x); o.y = f2bf(v.y); o.z = f2bf(v.z); o.w = f2bf(v.w);
      *(ushort4*)(dst + d) = o;
      const float dx = v.x - c.x, dy = v.y - c.y, dz = v.z - c.z, dw = v.w - c.w;
      s += dx * dx + dy * dy + dz * dz + dw * dw;
    }
    __shared__ float red[256];
    red[t] = s;
    __syncthreads();
    for (int st = 128; st > 0; st >>= 1) {
      if (t < st) red[t] += red[t + st];
      __syncthreads();
    }
    if (t == 0) {
      wbuf[i] = (red[0] > 1e-24f) ? 1.0f : 0.5f;
      if (i == 0) out[0] = 0.f;
    }
  } else {
    const int r = i - NROWS;
    const float* src = x_c + (size_t)r * D_DIM;
    ushortT* dst = A_enc + (size_t)i * D_DIM;
    for (int d = t * 4; d < D_DIM; d += 1024) {
      const float4 v = *(const float4*)(src + d);
      ushort4 o;
      o.x = f2bf(v.x); o.y = f2bf(v.y); o.z = f2bf(v.z); o.w = f2bf(v.w);
      *(ushort4*)(dst + d) = o;
    }
  }
}

// Batched transpose+cast of all six weights: W (KxN f32) -> WT (NxK bf16).
__global__ __launch_bounds__(256) void trans_all(
    const float* __restrict__ We1, const float* __restrict__ We2,
    const float* __restrict__ We3, const float* __restrict__ Wd1,
    const float* __restrict__ Wd2, const float* __restrict__ Wd3,
    ushortT* __restrict__ We1T, ushortT* __restrict__ We2T,
    ushortT* __restrict__ We3T, ushortT* __restrict__ Wd1T,
    ushortT* __restrict__ Wd2T, ushortT* __restrict__ Wd3T) {
  const int b = blockIdx.x;
  const float* W; ushortT* WT; int K, N, loc;
  if (b < 3072)      { W = We1; WT = We1T; K = 3072; N = 1024; loc = b; }
  else if (b < 4096) { W = We2; WT = We2T; K = 1024; N = 1024; loc = b - 3072; }
  else if (b < 4128) { W = We3; WT = We3T; K = 1024; N = 32;   loc = b - 4096; }
  else if (b < 4160) { W = Wd1; WT = Wd1T; K = 32;   N = 1024; loc = b - 4128; }
  else if (b < 5184) { W = Wd2; WT = Wd2T; K = 1024; N = 1024; loc = b - 4160; }
  else               { W = Wd3; WT = Wd3T; K = 1024; N = 3072; loc = b - 5184; }
  const int ntiles = N >> 5;
  const int n0 = (loc % ntiles) * 32;
  const int k0 = (loc / ntiles) * 32;
  __shared__ float tile[32][33];
  const int tx = threadIdx.x & 31;
  const int ty = threadIdx.x >> 5;
  for (int i = ty; i < 32; i += 8)
    tile[i][tx] = W[(size_t)(k0 + i) * N + n0 + tx];
  __syncthreads();
  for (int i = ty; i < 32; i += 8)
    WT[(size_t)(n0 + i) * K + k0 + tx] = f2bf(tile[tx][i]);
}

extern "C" void kernel_launch(void* const* d_in, const int* in_sizes, int n_in,
                              void* d_out, int out_size, void* d_ws, size_t ws_size,
                              hipStream_t stream) {
  const float* x_c = (const float*)d_in[0];
  const float* x_nn = (const float*)d_in[1];
  const float* We1 = (const float*)d_in[2];
  const float* be1 = (const float*)d_in[3];
  const float* We2 = (const float*)d_in[4];
  const float* be2 = (const float*)d_in[5];
  const float* We3 = (const float*)d_in[6];
  const float* be3 = (const float*)d_in[7];
  const float* Wd1 = (const float*)d_in[8];
  const float* bd1 = (const float*)d_in[9];
  const float* Wd2 = (const float*)d_in[10];
  const float* bd2 = (const float*)d_in[11];
  const float* Wd3 = (const float*)d_in[12];
  const float* bd3 = (const float*)d_in[13];
  float* out = (float*)d_out;

  char* p = (char*)d_ws;
  auto alloc = [&](size_t bytes) {
    char* r = p;
    p += (bytes + 255) & ~(size_t)255;
    return r;
  };
  ushortT* We1T = (ushortT*)alloc((size_t)H_DIM * D_DIM * 2);
  ushortT* We2T = (ushortT*)alloc((size_t)H_DIM * H_DIM * 2);
  ushortT* We3T = (ushortT*)alloc((size_t)Z_DIM * H_DIM * 2);
  ushortT* Wd1T = (ushortT*)alloc((size_t)H_DIM * Z_DIM * 2);
  ushortT* Wd2T = (ushortT*)alloc((size_t)H_DIM * H_DIM * 2);
  ushortT* Wd3T = (ushortT*)alloc((size_t)D_DIM * H_DIM * 2);
  ushortT* A_enc = (ushortT*)alloc((size_t)MENC * D_DIM * 2);
  ushortT* bufX = (ushortT*)alloc((size_t)MENC * H_DIM * 2);  // h1 / U1 / U2
  ushortT* bufY = (ushortT*)alloc((size_t)MENC * H_DIM * 2);  // h2 / A2 / t2
  ushortT* z = (ushortT*)alloc((size_t)MENC * Z_DIM * 2);
  // split-K partial buffer: max(4 planes of MENCxH f32, 8 of MENCxZ)
  float* Pbig = (float*)alloc((size_t)4 * MENC * H_DIM * 4);
  float* wbuf = (float*)alloc((size_t)NROWS * 4);

  const dim3 blk(256);
  const float* nofp = nullptr;
  const ushortT* nobf = nullptr;

  // x -> bf16, per-neighbor weights, zero loss accumulator; weights -> bf16^T
  prep_kernel<<<dim3(MENC), blk, 0, stream>>>(x_c, x_nn, A_enc, wbuf, out);
  trans_all<<<dim3(8256), blk, 0, stream>>>(We1, We2, We3, Wd1, Wd2, Wd3,
                                            We1T, We2T, We3T, Wd1T, Wd2T, Wd3T);

  // enc1: h1 = relu(A_enc @ We1 + be1). Split-K S=4 -> 1056 blocks
  // (4.1 streams/CU), Ks=768, nk=12.
  gemm64<EP_PART, 128><<<dim3(8, 33, 4), blk, 0, stream>>>(
      A_enc, We1T, nofp, nullptr, Pbig, MENC, H_DIM, D_DIM, D_DIM / 4,
      nobf, nofp, nullptr);
  reduce_lin<4, 1><<<dim3((MENC * H_DIM) / 1024), blk, 0, stream>>>(
      Pbig, be1, bufX, MENC * H_DIM, H_DIM - 1);

  // enc2: h2 = relu(h1 @ We2 + be2). Split-K S=2 -> 528 blocks, nk=8.
  gemm64<EP_PART, 128><<<dim3(8, 33, 2), blk, 0, stream>>>(
      bufX, We2T, nofp, nullptr, Pbig, MENC, H_DIM, H_DIM, H_DIM / 2,
      nobf, nofp, nullptr);
  reduce_lin<2, 1><<<dim3((MENC * H_DIM) / 1024), blk, 0, stream>>>(
      Pbig, be2, bufY, MENC * H_DIM, H_DIM - 1);

  // z = h2 @ We3 + be3 (N=32): split-K S=8 -> 264 blocks, nk=2.
  gemm64<EP_PART, 32><<<dim3(1, 33, 8), blk, 0, stream>>>(
      bufY, We3T, nofp, nullptr, Pbig, MENC, Z_DIM, H_DIM, H_DIM / 8,
      nobf, nofp, nullptr);
  reduce_lin<8, 0><<<dim3((MENC * Z_DIM) / 1024), blk, 0, stream>>>(
      Pbig, be3, z, MENC * Z_DIM, Z_DIM - 1);

  // linearized decoder with frozen center masks (exact for ReLU MLP):
  // U1 = [z_nn; z_c] @ Wd1 + bd1 (K=32, single tile)
  gemm_sb<EP_BIAS, 64><<<dim3(16, 33), blk, 0, stream>>>(
      z, Wd1T, bd1, bufX, MENC, H_DIM, Z_DIM, nobf, nofp, nullptr);
  // A2 = mask1 .* U1 (neighbors), relu(U1) (centers)
  mask_apply<<<dim3((MENC * H_DIM) / 1024), blk, 0, stream>>>(bufX, bufY);
  // U2 = A2 @ Wd2 + bd2 (raw, all rows). Split-K S=2.
  gemm64<EP_PART, 128><<<dim3(8, 33, 2), blk, 0, stream>>>(
      bufY, Wd2T, nofp, nullptr, Pbig, MENC, H_DIM, H_DIM, H_DIM / 2,
      nobf, nofp, nullptr);
  reduce_lin<2, 0><<<dim3((MENC * H_DIM) / 1024), blk, 0, stream>>>(
      Pbig, bd2, bufX, MENC * H_DIM, H_DIM - 1);
  // t2 = mask2 .* U2 (neighbor rows only)
  mask_apply<<<dim3((NROWS * H_DIM) / 1024), blk, 0, stream>>>(bufX, bufY);
  // loss GEMM: pred = t2 @ Wd3 + bd3, fused weighted-SSE vs bf16 x_nn
  // (768 blocks = 3 streams; 32KB LDS + VGPR<=128 allow it)
  gemm64<EP_LOSS, 128><<<dim3(24, 32, 1), blk, 0, stream>>>(
      bufY, Wd3T, bd3, nullptr, nullptr, NROWS, D_DIM, H_DIM, H_DIM,
      A_enc, wbuf, out);
}

// Round 8
// 359.008 us; speedup vs baseline: 1.1387x; 1.1387x over previous
//
#include <hip/hip_runtime.h>
#include <math.h>

#define D_DIM 3072
#define H_DIM 1024
#define Z_DIM 32
#define BATCH 128
#define NNEI 32
#define NROWS (BATCH * NNEI) /* 4096 */
#define MENC (NROWS + BATCH) /* 4224 */

typedef __attribute__((ext_vector_type(8))) short short8;
typedef __attribute__((ext_vector_type(4))) float f32x4;
typedef unsigned short ushortT;

__device__ __forceinline__ unsigned short f2bf(float f) {
  union { float f; unsigned int u; } v; v.f = f;
  unsigned int r = v.u + 0x7FFFu + ((v.u >> 16) & 1u);
  return (unsigned short)(r >> 16);
}
__device__ __forceinline__ float bf2f(unsigned short b) {
  union { unsigned int u; float f; } v; v.u = ((unsigned int)b) << 16;
  return v.f;
}

// Async global->LDS, 16B per lane. LDS dest is WAVE-UNIFORM base; HW adds
// lane*16. Global src is per-lane.
__device__ __forceinline__ void gl16(const ushortT* g, ushortT* l) {
  typedef __attribute__((address_space(1))) const void gvoid;
  typedef __attribute__((address_space(3))) void lvoid;
  __builtin_amdgcn_global_load_lds((gvoid*)(const void*)g, (lvoid*)(void*)l,
                                   16, 0, 0);
}
// Inline-asm ds_read_b128: invisible to SIInsertWaitcnts (avoids the
// conservative vmcnt(0) drain vs outstanding LDS-DMA; R14). Completion is
// OUR job: s_waitcnt lgkmcnt(0) + sched_barrier(0) before MFMAs (rule 18).
typedef __attribute__((address_space(3))) const ushortT lds_cus;
__device__ __forceinline__ short8 ldsr(const ushortT* p) {
  short8 r;
  asm volatile("ds_read_b128 %0, %1" : "=v"(r) : "v"((lds_cus*)p));
  return r;
}
#define BAR() asm volatile("s_barrier" ::: "memory")
#define VM0() asm volatile("s_waitcnt vmcnt(0)" ::: "memory")
#define LGKM0() asm volatile("s_waitcnt lgkmcnt(0)" ::: "memory")

template <int N>
__device__ __forceinline__ void vmw() {
  if constexpr (N == 0)      asm volatile("s_waitcnt vmcnt(0)" ::: "memory");
  else if constexpr (N == 2) asm volatile("s_waitcnt vmcnt(2)" ::: "memory");
  else if constexpr (N == 3) asm volatile("s_waitcnt vmcnt(3)" ::: "memory");
  else if constexpr (N == 4) asm volatile("s_waitcnt vmcnt(4)" ::: "memory");
}

enum { EP_RELU = 0, EP_BIAS = 1, EP_PART = 2, EP_LOSS = 3, EP_MASK1 = 4 };

// R14 ring-3 pipelined GEMM (best measured core; kept byte-identical).
// BM=128, BK=32, LDS ring of 3 tile-slots (48KB @TN=128), gl16 staging,
// 2-tile lookahead, ONE barrier per tile, counted vmcnt, asm ds_read.
// R16 note: six structurally different schedules (R0,R11-R15) all land at
// 283-380 TF on this problem size -- matches m102's family curve at
// N~2048-scale. This core is at its plateau; this round attacks the
// non-GEMM waste instead (mask fusions, transpose coalescing).
// R17: identical resubmit -- R16 bench died to container-acquisition infra
// failure (no pytest/dispatch data); source re-audited: no OOB, no
// divergent barriers, no unbounded loops.
// A: MxK bf16 row-major, BT: NxK bf16. M%128==0, N%TN==0, Ks%32==0, nk>=2.
template <int MODE, int TN>
__global__ __launch_bounds__(256) __attribute__((amdgpu_waves_per_eu(3)))
void gemm32(
    const ushortT* __restrict__ A, const ushortT* __restrict__ BT,
    const float* __restrict__ bias, ushortT* __restrict__ C,
    float* __restrict__ P, int M, int N, int K, int Ks,
    const ushortT* __restrict__ xa,    // EP_LOSS: M x N bf16 (x_nn)
    const float* __restrict__ wrow,    // EP_LOSS: per-row weight
    float* __restrict__ out) {
  constexpr int NF = TN / 32;   // 4 (TN=128), 2 (TN=64), 1 (TN=32)

  __shared__ __align__(16) ushortT As[3][4096];     // 3 x (128 x 32)
  __shared__ __align__(16) ushortT Bs[3][TN * 32];

  const int t = threadIdx.x;
  const int wave = t >> 6;
  const int lane = t & 63;
  const int quad = lane >> 4;
  const int lm = lane & 15;

  // XCD-bijective swizzle (FETCH 105->42MB). Only when nwg%8==0.
  int id = blockIdx.y * gridDim.x + blockIdx.x;
  const int nwg = gridDim.x * gridDim.y;
  if ((nwg & 7) == 0) id = (id & 7) * (nwg >> 3) + (id >> 3);
  const int bm = (id / gridDim.x) * 128;
  const int bn = (id % gridDim.x) * TN;

  const int koff = blockIdx.z * Ks;
  const int wr = (wave >> 1) * 64;
  const int wc = (wave & 1) * (TN / 2);

  f32x4 acc[4][NF];
#pragma unroll
  for (int i = 0; i < 4; ++i)
#pragma unroll
    for (int j = 0; j < NF; ++j) acc[i][j] = (f32x4)0.f;

  // staging: lane l -> (row = l&15, kq = l>>4); wave w owns chunks {2w,2w+1}
  const int srow = lane & 15;
  const int skq = lane >> 4;
  const ushortT* gA =
      A + (size_t)(bm + wave * 32 + srow) * K + koff + skq * 8;
  const size_t row16 = (size_t)16 * K;

  const ushortT* gB;
  if (TN == 128) {
    gB = BT + (size_t)(bn + wave * 32 + srow) * K + koff + skq * 8;
  } else if (TN == 64) {
    gB = BT + (size_t)(bn + wave * 16 + srow) * K + koff + skq * 8;
  } else {  // TN == 32: only waves 0,1 stage B (one chunk each)
    gB = BT + (size_t)(bn + (wave & 1) * 16 + srow) * K + koff + skq * 8;
  }

#define STAGE(kk, sl)                                           \
  {                                                             \
    const size_t o = (size_t)(kk) * 32;                         \
    ushortT* lA = &As[sl][wave * 1024];                         \
    gl16(gA + o, lA);                                           \
    gl16(gA + row16 + o, lA + 512);                             \
    if (TN == 128) {                                            \
      ushortT* lB = &Bs[sl][wave * 1024];                       \
      gl16(gB + o, lB);                                         \
      gl16(gB + row16 + o, lB + 512);                           \
    } else if (TN == 64) {                                      \
      gl16(gB + o, &Bs[sl][wave * 512]);                        \
    } else {                                                    \
      if (wave < 2) gl16(gB + o, &Bs[sl][(wave & 1) * 512]);    \
    }                                                           \
  }

  const int nk = Ks / 32;
  // prologue: 2-deep prefetch into slots 0,1
  STAGE(0, 0);
  if (nk > 1) STAGE(1, 1);

  int sl = 0;          // slot holding current tile
  int sn = 2;          // slot to stage (t0+2) into
  for (int t0 = 0; t0 < nk; ++t0) {
    // retire tile t0's DMAs: only tile-(t0+1)'s NLD loads may remain
    if (t0 + 1 < nk) {
      if (TN == 128) vmw<4>();
      else if (TN == 64) vmw<3>();
      else { if (wave < 2) vmw<3>(); else vmw<2>(); }
    } else {
      vmw<0>();
    }
    BAR();  // everyone's tile-t0 loads landed; slot sn free
    if (t0 + 2 < nk) STAGE(t0 + 2, sn);

    const ushortT* arp = &As[sl][(wr >> 4) * 512 + lane * 8];
    const ushortT* brp = &Bs[sl][(wc >> 4) * 512 + lane * 8];
    short8 af[4], bf[NF];
#pragma unroll
    for (int mt = 0; mt < 4; ++mt) af[mt] = ldsr(arp + mt * 512);
#pragma unroll
    for (int nt = 0; nt < NF; ++nt) bf[nt] = ldsr(brp + nt * 512);
    LGKM0();
    __builtin_amdgcn_sched_barrier(0);
#pragma unroll
    for (int mt = 0; mt < 4; ++mt)
#pragma unroll
      for (int nt = 0; nt < NF; ++nt)
        acc[mt][nt] = __builtin_amdgcn_mfma_f32_16x16x32_bf16(
            af[mt], bf[nt], acc[mt][nt], 0, 0, 0);

    sl = (sl == 2) ? 0 : sl + 1;
    sn = (sn == 2) ? 0 : sn + 1;
  }
#undef STAGE

  // C/D layout: col = lane&15, row = quad*4 + reg
  if (MODE == EP_LOSS) {
    __shared__ float red[256];
    float lsum = 0.f;
#pragma unroll
    for (int mt = 0; mt < 4; ++mt) {
#pragma unroll
      for (int r = 0; r < 4; ++r) {
        const int row = bm + wr + mt * 16 + quad * 4 + r;
        const float w = wrow[row];
        const ushortT* xr = xa + (size_t)row * N;
        float rs = 0.f;
#pragma unroll
        for (int nt = 0; nt < NF; ++nt) {
          const int col = bn + wc + nt * 16 + lm;
          const float d = bf2f(xr[col]) - (acc[mt][nt][r] + bias[col]);
          rs = fmaf(d, d, rs);
        }
        lsum = fmaf(w, rs, lsum);
      }
    }
    __syncthreads();
    red[t] = lsum;
    __syncthreads();
    for (int st = 128; st > 0; st >>= 1) {
      if (t < st) red[t] += red[t + st];
      __syncthreads();
    }
    if (t == 0) atomicAdd(out, red[0] * (1.0f / (float)NROWS));
  } else if (MODE == EP_PART) {
#pragma unroll
    for (int mt = 0; mt < 4; ++mt)
#pragma unroll
      for (int r = 0; r < 4; ++r) {
        const int row = bm + wr + mt * 16 + quad * 4 + r;
#pragma unroll
        for (int nt = 0; nt < NF; ++nt) {
          const int col = bn + wc + nt * 16 + lm;
          P[((size_t)blockIdx.z * M + row) * N + col] = acc[mt][nt][r];
        }
      }
  } else {
#pragma unroll
    for (int mt = 0; mt < 4; ++mt)
#pragma unroll
      for (int r = 0; r < 4; ++r) {
        const int row = bm + wr + mt * 16 + quad * 4 + r;
#pragma unroll
        for (int nt = 0; nt < NF; ++nt) {
          const int col = bn + wc + nt * 16 + lm;
          float v = acc[mt][nt][r] + bias[col];
          if (MODE == EP_RELU) v = fmaxf(v, 0.f);
          C[(size_t)row * N + col] = f2bf(v);
        }
      }
  }
}

// Single K=32 tile GEMM (dec L1): gload_lds + vmcnt(0) + one compute.
// R16: EP_MASK1 fuses the frozen-mask apply: every 16-row m-tile shares ONE
// center row ((bm+wr+mt*16)>>5 is constant across the tile), so the mask
// GEMM U1c = z_center @ Wd1 is one broadcast A-fragment (16B/lane, direct
// global read of L2-hot z) + 1 extra MFMA per (mt,nt). Epilogue emits
// A2 = (U1c+bias > 0) ? bf16(U1+bias) : 0 for neighbor blocks, relu for the
// center block (bm >= NROWS). Eliminates the mask_apply pass (~26 MB).
template <int MODE, int TN>
__global__ __launch_bounds__(256) void gemm_sb(
    const ushortT* __restrict__ A, const ushortT* __restrict__ BT,
    const float* __restrict__ bias, ushortT* __restrict__ C,
    int M, int N, int K,   // K must be 32
    const ushortT* __restrict__ xa, const float* __restrict__ wrow,
    float* __restrict__ out) {
  constexpr int NF = TN / 32;
  __shared__ __align__(16) ushortT As[4096];
  __shared__ __align__(16) ushortT Bs[TN * 32];

  const int t = threadIdx.x;
  const int wave = t >> 6;
  const int lane = t & 63;
  const int quad = lane >> 4;
  const int lm = lane & 15;

  int id = blockIdx.y * gridDim.x + blockIdx.x;
  const int nwg = gridDim.x * gridDim.y;
  if ((nwg & 7) == 0) id = (id & 7) * (nwg >> 3) + (id >> 3);
  const int bm = (id / gridDim.x) * 128;
  const int bn = (id % gridDim.x) * TN;

  const int wr = (wave >> 1) * 64;
  const int wc = (wave & 1) * (TN / 2);

  const int a_r0 = (t >> 6) * 16 + (t & 15);
  const int a_q8 = ((t >> 4) & 3) * 8;
  const ushortT* ga0 = A + (size_t)(bm + a_r0) * K + a_q8;
  const ushortT* gb0 = BT + (size_t)(bn + a_r0) * K + a_q8;

  ushortT* asw = &As[wave * 512];
  ushortT* bsw = &Bs[wave * 512];
  gl16(ga0, asw);
  gl16(ga0 + (size_t)64 * K, asw + 2048);
  gl16(gb0, bsw);
  if (TN == 128) gl16(gb0 + (size_t)64 * K, bsw + 2048);
  VM0();
  BAR();

  f32x4 acc[4][NF];
#pragma unroll
  for (int i = 0; i < 4; ++i)
#pragma unroll
    for (int j = 0; j < NF; ++j) acc[i][j] = (f32x4)0.f;

  const ushortT* arp = As + (wr >> 4) * 512 + lane * 8;
  const ushortT* brp = Bs + (wc >> 4) * 512 + lane * 8;
  short8 af[4], bf[NF];
#pragma unroll
  for (int mt = 0; mt < 4; ++mt) af[mt] = ldsr(arp + mt * 512);
#pragma unroll
  for (int nt = 0; nt < NF; ++nt) bf[nt] = ldsr(brp + nt * 512);
  LGKM0();
  __builtin_amdgcn_sched_barrier(0);
#pragma unroll
  for (int mt = 0; mt < 4; ++mt)
#pragma unroll
    for (int nt = 0; nt < NF; ++nt)
      acc[mt][nt] = __builtin_amdgcn_mfma_f32_16x16x32_bf16(
          af[mt], bf[nt], acc[mt][nt], 0, 0, 0);

  // mask GEMM: U1c = z_center @ Wd1 (broadcast A-frag; all 16 rows of an
  // m-tile share one center)
  f32x4 acc2[4][NF];
  if (MODE == EP_MASK1) {
#pragma unroll
    for (int i = 0; i < 4; ++i)
#pragma unroll
      for (int j = 0; j < NF; ++j) acc2[i][j] = (f32x4)0.f;
    if (bm < NROWS) {
      short8 az[4];
#pragma unroll
      for (int mt = 0; mt < 4; ++mt) {
        const int cz = NROWS + ((bm + wr + mt * 16) >> 5);
        az[mt] = *(const short8*)(A + (size_t)cz * K + ((lane >> 4) << 3));
      }
#pragma unroll
      for (int mt = 0; mt < 4; ++mt)
#pragma unroll
        for (int nt = 0; nt < NF; ++nt)
          acc2[mt][nt] = __builtin_amdgcn_mfma_f32_16x16x32_bf16(
              az[mt], bf[nt], acc2[mt][nt], 0, 0, 0);
    }
  }

  if (MODE == EP_MASK1) {
    const bool nb = (bm < NROWS);
#pragma unroll
    for (int mt = 0; mt < 4; ++mt)
#pragma unroll
      for (int r = 0; r < 4; ++r) {
        const int row = bm + wr + mt * 16 + quad * 4 + r;
#pragma unroll
        for (int nt = 0; nt < NF; ++nt) {
          const int col = bn + wc + nt * 16 + lm;
          const float v = acc[mt][nt][r] + bias[col];
          ushortT o;
          if (nb) {
            const float m = acc2[mt][nt][r] + bias[col];
            o = (m > 0.f) ? f2bf(v) : (ushortT)0;
          } else {
            o = f2bf(fmaxf(v, 0.f));
          }
          C[(size_t)row * N + col] = o;
        }
      }
  } else {
#pragma unroll
    for (int mt = 0; mt < 4; ++mt)
#pragma unroll
      for (int r = 0; r < 4; ++r) {
        const int row = bm + wr + mt * 16 + quad * 4 + r;
#pragma unroll
        for (int nt = 0; nt < NF; ++nt) {
          const int col = bn + wc + nt * 16 + lm;
          float v = acc[mt][nt][r] + bias[col];
          if (MODE == EP_RELU) v = fmaxf(v, 0.f);
          C[(size_t)row * N + col] = f2bf(v);
        }
      }
  }
}

// sum split-K fp32 partials + bias (+optional relu) -> bf16. N power of 2.
template <int S, int RELU>
__global__ __launch_bounds__(256) void reduce_lin(
    const float* __restrict__ P, const float* __restrict__ bias,
    ushortT* __restrict__ outp, int MN, int Nmask) {
  const int i4 = (blockIdx.x * 256 + threadIdx.x) * 4;
  if (i4 >= MN) return;
  float4 s = *(const float4*)(P + i4);
#pragma unroll
  for (int k = 1; k < S; ++k) {
    const float4 q = *(const float4*)(P + (size_t)k * MN + i4);
    s.x += q.x; s.y += q.y; s.z += q.z; s.w += q.w;
  }
  const float4 b = *(const float4*)(bias + (i4 & Nmask));
  float vx = s.x + b.x, vy = s.y + b.y, vz = s.z + b.z, vw = s.w + b.w;
  if (RELU) {
    vx = fmaxf(vx, 0.f); vy = fmaxf(vy, 0.f);
    vz = fmaxf(vz, 0.f); vw = fmaxf(vw, 0.f);
  }
  ushort4 o;
  o.x = f2bf(vx); o.y = f2bf(vy); o.z = f2bf(vz); o.w = f2bf(vw);
  *(ushort4*)(outp + i4) = o;
}

// R16: fused split-K reduce + frozen-mask apply for dec L2.
// t2 = (U2[center]>0) ? bf16(U2) : 0 for the NROWS neighbor rows, where U2
// (own row AND center row) is re-summed from the S partial planes + bias.
// Center-row reads are 32x-reused -> L2-hot. U2 is never materialized.
template <int S>
__global__ __launch_bounds__(256) void reduce_lin_mask(
    const float* __restrict__ P, const float* __restrict__ bias,
    ushortT* __restrict__ outp, int MN /* NROWS*H */, int MNfull /* MENC*H */) {
  const int i4 = (blockIdx.x * 256 + threadIdx.x) * 4;
  if (i4 >= MN) return;
  const int r = i4 >> 10;
  const int c = i4 & 1023;
  const size_t ci = (((size_t)(NROWS + (r >> 5))) << 10) + c;
  float4 s = *(const float4*)(P + i4);
  float4 sc = *(const float4*)(P + ci);
#pragma unroll
  for (int k = 1; k < S; ++k) {
    const float4 q = *(const float4*)(P + (size_t)k * MNfull + i4);
    const float4 qc = *(const float4*)(P + (size_t)k * MNfull + ci);
    s.x += q.x; s.y += q.y; s.z += q.z; s.w += q.w;
    sc.x += qc.x; sc.y += qc.y; sc.z += qc.z; sc.w += qc.w;
  }
  const float4 b = *(const float4*)(bias + c);
  const float ux = s.x + b.x, uy = s.y + b.y, uz = s.z + b.z, uw = s.w + b.w;
  const float mx = sc.x + b.x, my = sc.y + b.y, mz = sc.z + b.z,
              mw = sc.w + b.w;
  ushort4 o;
  o.x = (mx > 0.f) ? f2bf(ux) : (ushortT)0;
  o.y = (my > 0.f) ? f2bf(uy) : (ushortT)0;
  o.z = (mz > 0.f) ? f2bf(uz) : (ushortT)0;
  o.w = (mw > 0.f) ? f2bf(uw) : (ushortT)0;
  *(ushort4*)(outp + i4) = o;
}

// Fused prep: x fp32 -> bf16 A_enc; per-(b,n) weights from dist^2; zero out[0].
__global__ __launch_bounds__(256) void prep_kernel(
    const float* __restrict__ x_c, const float* __restrict__ x_nn,
    ushortT* __restrict__ A_enc, float* __restrict__ wbuf, float* __restrict__ out) {
  const int i = blockIdx.x;
  const int t = threadIdx.x;
  if (i < NROWS) {
    const float* src = x_nn + (size_t)i * D_DIM;
    const float* ctr = x_c + (size_t)(i >> 5) * D_DIM;
    ushortT* dst = A_enc + (size_t)i * D_DIM;
    float s = 0.f;
    for (int d = t * 4; d < D_DIM; d += 1024) {
      const float4 v = *(const float4*)(src + d);
      const float4 c = *(const float4*)(ctr + d);
      ushort4 o;
      o.x = f2bf(v.x); o.y = f2bf(v.y); o.z = f2bf(v.z); o.w = f2bf(v.w);
      *(ushort4*)(dst + d) = o;
      const float dx = v.x - c.x, dy = v.y - c.y, dz = v.z - c.z, dw = v.w - c.w;
      s += dx * dx + dy * dy + dz * dz + dw * dw;
    }
    __shared__ float red[256];
    red[t] = s;
    __syncthreads();
    for (int st = 128; st > 0; st >>= 1) {
      if (t < st) red[t] += red[t + st];
      __syncthreads();
    }
    if (t == 0) {
      wbuf[i] = (red[0] > 1e-24f) ? 1.0f : 0.5f;
      if (i == 0) out[0] = 0.f;
    }
  } else {
    const int r = i - NROWS;
    const float* src = x_c + (size_t)r * D_DIM;
    ushortT* dst = A_enc + (size_t)i * D_DIM;
    for (int d = t * 4; d < D_DIM; d += 1024) {
      const float4 v = *(const float4*)(src + d);
      ushort4 o;
      o.x = f2bf(v.x); o.y = f2bf(v.y); o.z = f2bf(v.z); o.w = f2bf(v.w);
      *(ushort4*)(dst + d) = o;
    }
  }
}

// Batched transpose+cast of all six weights: W (KxN f32) -> WT (NxK bf16).
// R16: write phase re-mapped for coalescing: thread -> (n = tid>>3,
// kq = tid&7), each emits a ushort4 (4 consecutive k) => 32-thread n-rows
// write 256B contiguous (was 2B/thread scattered, 64B segments).
__global__ __launch_bounds__(256) void trans_all(
    const float* __restrict__ We1, const float* __restrict__ We2,
    const float* __restrict__ We3, const float* __restrict__ Wd1,
    const float* __restrict__ Wd2, const float* __restrict__ Wd3,
    ushortT* __restrict__ We1T, ushortT* __restrict__ We2T,
    ushortT* __restrict__ We3T, ushortT* __restrict__ Wd1T,
    ushortT* __restrict__ Wd2T, ushortT* __restrict__ Wd3T) {
  const int b = blockIdx.x;
  const float* W; ushortT* WT; int K, N, loc;
  if (b < 3072)      { W = We1; WT = We1T; K = 3072; N = 1024; loc = b; }
  else if (b < 4096) { W = We2; WT = We2T; K = 1024; N = 1024; loc = b - 3072; }
  else if (b < 4128) { W = We3; WT = We3T; K = 1024; N = 32;   loc = b - 4096; }
  else if (b < 4160) { W = Wd1; WT = Wd1T; K = 32;   N = 1024; loc = b - 4128; }
  else if (b < 5184) { W = Wd2; WT = Wd2T; K = 1024; N = 1024; loc = b - 4160; }
  else               { W = Wd3; WT = Wd3T; K = 1024; N = 3072; loc = b - 5184; }
  const int ntiles = N >> 5;
  const int n0 = (loc % ntiles) * 32;
  const int k0 = (loc / ntiles) * 32;
  __shared__ float tile[32][33];
  const int tx = threadIdx.x & 31;
  const int ty = threadIdx.x >> 5;
  for (int i = ty; i < 32; i += 8)
    tile[i][tx] = W[(size_t)(k0 + i) * N + n0 + tx];
  __syncthreads();
  const int n = threadIdx.x >> 3;
  const int kq = (threadIdx.x & 7) * 4;
  ushort4 o;
  o.x = f2bf(tile[kq + 0][n]);
  o.y = f2bf(tile[kq + 1][n]);
  o.z = f2bf(tile[kq + 2][n]);
  o.w = f2bf(tile[kq + 3][n]);
  *(ushort4*)(WT + (size_t)(n0 + n) * K + k0 + kq) = o;
}

extern "C" void kernel_launch(void* const* d_in, const int* in_sizes, int n_in,
                              void* d_out, int out_size, void* d_ws, size_t ws_size,
                              hipStream_t stream) {
  const float* x_c = (const float*)d_in[0];
  const float* x_nn = (const float*)d_in[1];
  const float* We1 = (const float*)d_in[2];
  const float* be1 = (const float*)d_in[3];
  const float* We2 = (const float*)d_in[4];
  const float* be2 = (const float*)d_in[5];
  const float* We3 = (const float*)d_in[6];
  const float* be3 = (const float*)d_in[7];
  const float* Wd1 = (const float*)d_in[8];
  const float* bd1 = (const float*)d_in[9];
  const float* Wd2 = (const float*)d_in[10];
  const float* bd2 = (const float*)d_in[11];
  const float* Wd3 = (const float*)d_in[12];
  const float* bd3 = (const float*)d_in[13];
  float* out = (float*)d_out;

  char* p = (char*)d_ws;
  auto alloc = [&](size_t bytes) {
    char* r = p;
    p += (bytes + 255) & ~(size_t)255;
    return r;
  };
  ushortT* We1T = (ushortT*)alloc((size_t)H_DIM * D_DIM * 2);
  ushortT* We2T = (ushortT*)alloc((size_t)H_DIM * H_DIM * 2);
  ushortT* We3T = (ushortT*)alloc((size_t)Z_DIM * H_DIM * 2);
  ushortT* Wd1T = (ushortT*)alloc((size_t)H_DIM * Z_DIM * 2);
  ushortT* Wd2T = (ushortT*)alloc((size_t)H_DIM * H_DIM * 2);
  ushortT* Wd3T = (ushortT*)alloc((size_t)D_DIM * H_DIM * 2);
  ushortT* A_enc = (ushortT*)alloc((size_t)MENC * D_DIM * 2);
  ushortT* bufX = (ushortT*)alloc((size_t)MENC * H_DIM * 2);  // h1 / t2
  ushortT* bufY = (ushortT*)alloc((size_t)MENC * H_DIM * 2);  // h2 / A2
  ushortT* z = (ushortT*)alloc((size_t)MENC * Z_DIM * 2);
  // split-K partial buffer: max(3 planes of MENCxH f32, 8 of MENCxZ)
  float* Pbig = (float*)alloc((size_t)3 * MENC * H_DIM * 4);
  float* wbuf = (float*)alloc((size_t)NROWS * 4);

  const dim3 blk(256);
  const float* nofp = nullptr;
  const ushortT* nobf = nullptr;

  // x -> bf16, per-neighbor weights, zero loss accumulator; weights -> bf16^T
  prep_kernel<<<dim3(MENC), blk, 0, stream>>>(x_c, x_nn, A_enc, wbuf, out);
  trans_all<<<dim3(8256), blk, 0, stream>>>(We1, We2, We3, Wd1, Wd2, Wd3,
                                            We1T, We2T, We3T, Wd1T, Wd2T, Wd3T);

  // enc1: h1 = relu(A_enc @ We1 + be1). Split-K S=3 -> 792 blocks.
  gemm32<EP_PART, 128><<<dim3(8, 33, 3), blk, 0, stream>>>(
      A_enc, We1T, nofp, nullptr, Pbig, MENC, H_DIM, D_DIM, D_DIM / 3,
      nobf, nofp, nullptr);
  reduce_lin<3, 1><<<dim3((MENC * H_DIM) / 1024), blk, 0, stream>>>(
      Pbig, be1, bufX, MENC * H_DIM, H_DIM - 1);

  // enc2: h2 = relu(h1 @ We2 + be2). Split-K S=2 -> 528 blocks.
  gemm32<EP_PART, 128><<<dim3(8, 33, 2), blk, 0, stream>>>(
      bufX, We2T, nofp, nullptr, Pbig, MENC, H_DIM, H_DIM, H_DIM / 2,
      nobf, nofp, nullptr);
  reduce_lin<2, 1><<<dim3((MENC * H_DIM) / 1024), blk, 0, stream>>>(
      Pbig, be2, bufY, MENC * H_DIM, H_DIM - 1);

  // z = h2 @ We3 + be3 (N=32): split-K S=8 -> 264 blocks, 4 tiles each
  gemm32<EP_PART, 32><<<dim3(1, 33, 8), blk, 0, stream>>>(
      bufY, We3T, nofp, nullptr, Pbig, MENC, Z_DIM, H_DIM, H_DIM / 8,
      nobf, nofp, nullptr);
  reduce_lin<8, 0><<<dim3((MENC * Z_DIM) / 1024), blk, 0, stream>>>(
      Pbig, be3, z, MENC * Z_DIM, Z_DIM - 1);

  // linearized decoder with frozen center masks (exact for ReLU MLP):
  // dec L1 + fused mask1: A2 = (U1c>0)?U1:0 (neighbors), relu(U1) (centers)
  gemm_sb<EP_MASK1, 64><<<dim3(16, 33), blk, 0, stream>>>(
      z, Wd1T, bd1, bufY, MENC, H_DIM, Z_DIM, nobf, nofp, nullptr);
  // U2 = A2 @ Wd2 + bd2 (partials, all rows). Split-K S=2.
  gemm32<EP_PART, 128><<<dim3(8, 33, 2), blk, 0, stream>>>(
      bufY, Wd2T, nofp, nullptr, Pbig, MENC, H_DIM, H_DIM, H_DIM / 2,
      nobf, nofp, nullptr);
  // t2 = (U2c>0)?U2:0 directly from partials (fused mask2; U2 never stored)
  reduce_lin_mask<2><<<dim3((NROWS * H_DIM) / 1024), blk, 0, stream>>>(
      Pbig, bd2, bufX, NROWS * H_DIM, MENC * H_DIM);
  // loss GEMM: pred = t2 @ Wd3 + bd3, fused weighted-SSE vs bf16 x_nn
  gemm32<EP_LOSS, 128><<<dim3(24, 32, 1), blk, 0, stream>>>(
      bufX, Wd3T, bd3, nullptr, nullptr, NROWS, D_DIM, H_DIM, H_DIM,
      A_enc, wbuf, out);
}